// Round 7
// baseline (245.705 us; speedup 1.0000x reference)
//
#include <hip/hip_runtime.h>
#include <hip/hip_bf16.h>

typedef __attribute__((ext_vector_type(8))) short bf16x8;
typedef __attribute__((ext_vector_type(4))) float f32x4;

__device__ __forceinline__ float bf2f(unsigned short u) {
  return __uint_as_float(((unsigned int)u) << 16);
}
__device__ __forceinline__ unsigned short f2bf(float f) {
  unsigned int u = __float_as_uint(f);
  u += 0x7fffu + ((u >> 16) & 1u);
  return (unsigned short)(u >> 16);
}

// ---------------- workspace layout (bytes) ----------------
constexpr size_t OFF_XPAD = 0;
constexpr size_t SZ_XPAD  = (size_t)8 * 66 * 66 * 128 * 2;        // 8,921,088
constexpr size_t OFF_WB   = OFF_XPAD + SZ_XPAD;
constexpr size_t SZ_WB    = (size_t)9 * 16 * 256 * 8 * 2;         // 589,824
constexpr size_t OFF_WS2  = OFF_WB + SZ_WB;
constexpr size_t SZ_WS2   = (size_t)16 * 256 * 8 * 2;             // 65,536
constexpr size_t OFF_WO   = OFF_WS2 + SZ_WS2;
constexpr size_t SZ_WO    = (size_t)9 * 16 * 32 * 8 * 2;          // 73,728
constexpr size_t OFF_PART = OFF_WO + SZ_WO;
constexpr size_t SZ_PART  = (size_t)512 * 256 * 2 * 4;            // 1,048,576
constexpr size_t OFF_STAT = OFF_PART + SZ_PART;
constexpr size_t SZ_STAT  = (size_t)256 * 2 * 4;                  // 2,048
constexpr size_t OFF_CNT  = OFF_STAT + SZ_STAT;
constexpr size_t SZ_CNT   = 2 * 4;

// ---------------- device-scope grid barrier (co-residency guaranteed by launch math) ----------------
__device__ __forceinline__ void grid_barrier(unsigned int* cnt, unsigned int target) {
  __syncthreads();
  if (threadIdx.x == 0) {
    __threadfence();                                   // release: partials/stats visible device-wide
    __hip_atomic_fetch_add(cnt, 1u, __ATOMIC_ACQ_REL, __HIP_MEMORY_SCOPE_AGENT);
    while (__hip_atomic_load(cnt, __ATOMIC_ACQUIRE, __HIP_MEMORY_SCOPE_AGENT) < target) {
      __builtin_amdgcn_s_sleep(16);
    }
  }
  __syncthreads();
}

// ---------------- prep: pad-transpose x (incl. borders) + weight pack ----------------
__global__ __launch_bounds__(256) void k_prep(const float* __restrict__ x,
                                              const float* __restrict__ wdef,
                                              const float* __restrict__ wsc,
                                              const float* __restrict__ woff,
                                              unsigned short* __restrict__ xp,
                                              unsigned short* __restrict__ wB,
                                              unsigned short* __restrict__ wS,
                                              unsigned short* __restrict__ wO) {
  int blk = blockIdx.x;
  int t = threadIdx.x;
  if (blk < 1024) {                   // interior rows: NCHW fp32 -> NHWC bf16
    int b = blk >> 7, h = (blk >> 1) & 63, chalf = blk & 1;
    __shared__ float tile[16][66];
    for (int cc = 0; cc < 4; ++cc) {
      int c0 = (chalf * 4 + cc) * 16;
      int wr = t & 63, cl = t >> 6;
#pragma unroll
      for (int i = 0; i < 4; ++i) {
        int c = c0 + cl * 4 + i;
        tile[cl * 4 + i][wr] = x[(((size_t)b * 128 + c) * 64 + h) * 64 + wr];
      }
      __syncthreads();
      int ww = t >> 2, cq = t & 3;
      ushort4 u4;
      u4.x = f2bf(tile[cq * 4 + 0][ww]);
      u4.y = f2bf(tile[cq * 4 + 1][ww]);
      u4.z = f2bf(tile[cq * 4 + 2][ww]);
      u4.w = f2bf(tile[cq * 4 + 3][ww]);
      *(ushort4*)(xp + ((size_t)(b * 66 + h + 1) * 66 + (ww + 1)) * 128 + c0 + cq * 4) = u4;
      __syncthreads();
    }
  } else if (blk < 1040) {            // border rows (hp = 0 or 65): zeros
    int idx = blk - 1024;
    int b = idx >> 1, hp = (idx & 1) ? 65 : 0;
    unsigned short* base = xp + (size_t)(b * 66 + hp) * 66 * 128;
    uint4 z = {0u, 0u, 0u, 0u};
#pragma unroll
    for (int it = 0; it < 5; ++it) {
      int i = it * 256 + t;
      if (i < 1056) *(uint4*)(base + i * 8) = z;
    }
  } else if (blk < 1056) {            // border cols (px = 0 or 65), rows 1..64: zeros
    int idx = blk - 1040;
    int b = idx >> 1, px = (idx & 1) ? 65 : 0;
    uint4 z = {0u, 0u, 0u, 0u};
#pragma unroll
    for (int it = 0; it < 4; ++it) {
      int row = it * 16 + (t >> 4);
      int off = t & 15;
      *(uint4*)(xp + ((size_t)(b * 66 + 1 + row) * 66 + px) * 128 + off * 8) = z;
    }
  } else {                            // weight packing
    int tid = (blk - 1056) * 256 + t;
    if (tid < 294912) {
      int k8 = tid & 7, n = (tid >> 3) & 255, kb = (tid >> 11) & 15, tap = tid >> 15;
      int c = kb * 8 + k8;
      wB[tid] = f2bf(wdef[((size_t)n * 128 + c) * 9 + tap]);
    } else if (tid < 294912 + 32768) {
      int i = tid - 294912;
      int k8 = i & 7, n = (i >> 3) & 255, kb = i >> 11;
      wS[i] = f2bf(wsc[(size_t)n * 128 + kb * 8 + k8]);
    } else if (tid < 294912 + 32768 + 36864) {
      int i = tid - 327680;
      int k8 = i & 7, n = (i >> 3) & 31, kb = (i >> 8) & 15, tap = i >> 12;
      int c = kb * 8 + k8;
      wO[i] = f2bf(n < 18 ? woff[((size_t)n * 128 + c) * 9 + tap] : 0.f);
    }
  }
}

// ---------------- fused: offset conv + deform conv + BN stats + shortcut + BN/ReLU store ----------------
// 512 blocks x 512 thr (8 waves). Waves 0-3 = MFMA consumers (64px x 256ch in acc[4][4]);
// waves 4-7 = sampling producers. Manual grid barriers; y never leaves registers.
__global__ __launch_bounds__(512, 4) void k_coop(const unsigned short* __restrict__ xp,
                                                 const unsigned short* __restrict__ wB,
                                                 const unsigned short* __restrict__ wS,
                                                 const unsigned short* __restrict__ wO,
                                                 const float* __restrict__ boff,
                                                 const float* __restrict__ bdef,
                                                 const float* __restrict__ gamma,
                                                 const float* __restrict__ beta,
                                                 const float* __restrict__ bsc,
                                                 float* __restrict__ partials,
                                                 float* __restrict__ stats,
                                                 unsigned int* __restrict__ cnt,
                                                 float* __restrict__ out) {
  int rt = blockIdx.x;                // rowtile: b*64 + h
  int b = rt >> 6, h = rt & 63;
  int t = threadIdx.x;
  int lane = t & 63, wid = t >> 6;    // 8 waves
  int m = lane & 15, quad = lane >> 4;
  bool consumer = wid < 4;
  __shared__ __align__(16) unsigned short At[2][64 * 136];  // 34816 B (also yb in phase 3)
  __shared__ __align__(16) unsigned short sb[256 * 68];     // 34816 B (shortcut tile)
  __shared__ float offsL[9][64][2];                         // 4608 B (also stats scratch)

  // ---- phase 0: offset conv on PRODUCER waves (4 x 16 px) ----
  if (!consumer) {
    int pw = wid - 4;
    f32x4 a0 = {0.f, 0.f, 0.f, 0.f}, a1 = {0.f, 0.f, 0.f, 0.f};
    int px = pw * 16 + m;
    const unsigned short* xbase = xp + ((size_t)(b * 66 + h) * 66 + px) * 128 + quad * 8;
    for (int tap = 0; tap < 9; ++tap) {
      const unsigned short* arow = xbase + ((tap / 3) * 66 + (tap % 3)) * 128;
#pragma unroll
      for (int kk = 0; kk < 4; ++kk) {
        bf16x8 a = *(const bf16x8*)(arow + kk * 32);
        const unsigned short* bb = wO + (size_t)(tap * 16 + kk * 4 + quad) * 256;
        bf16x8 b0 = *(const bf16x8*)(bb + m * 8);
        bf16x8 b1 = *(const bf16x8*)(bb + (16 + m) * 8);
        a0 = __builtin_amdgcn_mfma_f32_16x16x32_bf16(a, b0, a0, 0, 0, 0);
        a1 = __builtin_amdgcn_mfma_f32_16x16x32_bf16(a, b1, a1, 0, 0, 0);
      }
    }
#pragma unroll
    for (int r = 0; r < 4; ++r) {
      int pxs = pw * 16 + quad * 4 + r;
      offsL[m >> 1][pxs][m & 1] = a0[r] + boff[m];
      if (m < 2) offsL[8][pxs][m] = a1[r] + boff[16 + m];
    }
  }
  __syncthreads();

  // ---- producer sampling helpers ----
  int pl = t & 255;                   // producer-local index
  int px_s = pl >> 2, sub = pl & 3;   // 64 px x 4 sub (16B each -> 64B line per 4 lanes)
  const unsigned short* xb_base = xp + (size_t)b * 66 * 66 * 128;

  auto sample_prep = [&](int tap, float* wgt, const unsigned short** p) {
    float2 ov = *(const float2*)&offsL[tap][px_s][0];
    int ky = tap / 3 - 1, kx = tap % 3 - 1;
    float py = (float)(h + ky) + ov.x;
    float pxf = (float)(px_s + kx) + ov.y;
    float y0f = floorf(py), x0f = floorf(pxf);
    float fy = py - y0f, fx = pxf - x0f;
    int iy0 = (int)y0f, ix0 = (int)x0f;
#pragma unroll
    for (int j = 0; j < 4; ++j) {
      int iy = iy0 + (j >> 1), ix = ix0 + (j & 1);
      float wy = (j >> 1) ? fy : 1.f - fy;
      float wx = (j & 1) ? fx : 1.f - fx;
      bool valid = (iy >= 0) && (iy < 64) && (ix >= 0) && (ix < 64);
      int iyc = min(max(iy, 0), 63), ixc = min(max(ix, 0), 63);
      wgt[j] = valid ? wy * wx : 0.f;
      p[j] = xb_base + ((size_t)(iyc + 1) * 66 + (ixc + 1)) * 128 + sub * 8;
    }
  };
  auto sample_tap = [&](int tap, unsigned short* dst) {
    float wgt[4]; const unsigned short* p[4];
    sample_prep(tap, wgt, p);
#pragma unroll
    for (int g0 = 0; g0 < 4; g0 += 2) {
      bf16x8 v[2][4];
#pragma unroll
      for (int gg = 0; gg < 2; ++gg)
#pragma unroll
        for (int j = 0; j < 4; ++j)
          v[gg][j] = *(const bf16x8*)(p[j] + (g0 + gg) * 32);
#pragma unroll
      for (int gg = 0; gg < 2; ++gg) {
        bf16x8 o;
#pragma unroll
        for (int j = 0; j < 8; ++j) {
          float s = fmaf(wgt[0], bf2f((unsigned short)v[gg][0][j]),
                    fmaf(wgt[1], bf2f((unsigned short)v[gg][1][j]),
                    fmaf(wgt[2], bf2f((unsigned short)v[gg][2][j]),
                         wgt[3] * bf2f((unsigned short)v[gg][3][j]))));
          o[j] = (short)f2bf(s);
        }
        *(bf16x8*)(dst + (g0 + gg) * 32) = o;
      }
    }
  };

  // ---- consumer accumulator: 64 px x 64 ch per wave (N = wid*64) ----
  f32x4 acc[4][4];
  if (consumer) {
#pragma unroll
    for (int i = 0; i < 4; ++i)
#pragma unroll
      for (int j = 0; j < 4; ++j) acc[i][j] = (f32x4){0.f, 0.f, 0.f, 0.f};
  }
  int nb = wid * 64;                  // consumer N range

  // prologue: producers sample tap 0 into buf 0
  if (!consumer) sample_tap(0, &At[0][px_s * 136 + sub * 8]);
  __syncthreads();

#pragma unroll
  for (int tap = 0; tap < 9; ++tap) {
    if (consumer) {
      const unsigned short* cur = At[tap & 1];
#pragma unroll
      for (int kk = 0; kk < 4; ++kk) {
        bf16x8 af[4];
#pragma unroll
        for (int ms = 0; ms < 4; ++ms)
          af[ms] = *(const bf16x8*)(cur + (ms * 16 + m) * 136 + kk * 32 + quad * 8);
#pragma unroll
        for (int ns = 0; ns < 4; ++ns) {
          bf16x8 bfr = *(const bf16x8*)(wB + ((size_t)(tap * 16 + kk * 4 + quad) * 256 + nb + ns * 16 + m) * 8);
#pragma unroll
          for (int ms = 0; ms < 4; ++ms)
            acc[ms][ns] = __builtin_amdgcn_mfma_f32_16x16x32_bf16(af[ms], bfr, acc[ms][ns], 0, 0, 0);
        }
      }
    } else if (tap < 8) {
      sample_tap(tap + 1, &At[(tap + 1) & 1][px_s * 136 + sub * 8]);
    }
    __syncthreads();
  }

  // ---- phase 1 epilogue: BN partials from registers (consumers) ----
  if (consumer) {
#pragma unroll
    for (int ns = 0; ns < 4; ++ns) {
      int n = nb + ns * 16 + m;
      float bias = bdef[n];
      float s = 0.f, q = 0.f;
#pragma unroll
      for (int ms = 0; ms < 4; ++ms)
#pragma unroll
        for (int r = 0; r < 4; ++r) {
          float v = acc[ms][ns][r] + bias;
          s += v; q += v * v;
        }
      s += __shfl_xor(s, 16); s += __shfl_xor(s, 32);
      q += __shfl_xor(q, 16); q += __shfl_xor(q, 32);
      if (quad == 0) {
        partials[((size_t)rt * 256 + n) * 2 + 0] = s;
        partials[((size_t)rt * 256 + n) * 2 + 1] = q;
      }
    }
  }

  grid_barrier(cnt + 0, 512);

  // ---- stats: blocks 0..255 reduce one channel each ----
  if (rt < 256) {
    int ch = rt;
    int row = wid * 64 + lane;
    float s = partials[((size_t)row * 256 + ch) * 2 + 0];
    float q = partials[((size_t)row * 256 + ch) * 2 + 1];
#pragma unroll
    for (int d = 1; d < 64; d <<= 1) { s += __shfl_xor(s, d); q += __shfl_xor(q, d); }
    float* red = &offsL[0][0][0];
    if (lane == 0) { red[wid * 2] = s; red[wid * 2 + 1] = q; }
    __syncthreads();
    if (wid == 0 && lane < 8) {
      s = red[lane * 2]; q = red[lane * 2 + 1];
#pragma unroll
      for (int d = 1; d < 8; d <<= 1) { s += __shfl_xor(s, d); q += __shfl_xor(q, d); }
      if (lane == 0) {
        float mean = s * (1.f / 32768.f);
        float var = q * (1.f / 32768.f) - mean * mean;
        float A = gamma[ch] * rsqrtf(var + 1e-5f);
        stats[ch * 2 + 0] = A;
        stats[ch * 2 + 1] = beta[ch] - mean * A;
      }
    }
  }

  grid_barrier(cnt + 1, 512);

  // ---- phase 3a: consumers apply BN in-register, park bf16 into yb (At) ----
  unsigned short* yb = &At[0][0];     // [256 ch][68 px]
  if (consumer) {
#pragma unroll
    for (int ns = 0; ns < 4; ++ns) {
      int n = nb + ns * 16 + m;
      float bias = bdef[n];
      float A = stats[n * 2], Bc = stats[n * 2 + 1];
#pragma unroll
      for (int ms = 0; ms < 4; ++ms) {
        ushort4 u;
        u.x = f2bf(fmaf(acc[ms][ns][0] + bias, A, Bc));
        u.y = f2bf(fmaf(acc[ms][ns][1] + bias, A, Bc));
        u.z = f2bf(fmaf(acc[ms][ns][2] + bias, A, Bc));
        u.w = f2bf(fmaf(acc[ms][ns][3] + bias, A, Bc));
        *(ushort4*)(yb + n * 68 + ms * 16 + quad * 4) = u;
      }
    }
  }
  // ---- phase 3b: producers compute 1x1 shortcut (64 px x 64 ch each) into sb ----
  if (!consumer) {
    int nbp = (wid - 4) * 64;
    const unsigned short* xrow = xp + ((size_t)(b * 66 + h + 1) * 66 + 1) * 128;
    f32x4 acc2[4][4];
#pragma unroll
    for (int i = 0; i < 4; ++i)
#pragma unroll
      for (int j = 0; j < 4; ++j) acc2[i][j] = (f32x4){0.f, 0.f, 0.f, 0.f};
#pragma unroll
    for (int kk = 0; kk < 4; ++kk) {
      bf16x8 xf[4];
#pragma unroll
      for (int ms = 0; ms < 4; ++ms)
        xf[ms] = *(const bf16x8*)(xrow + (ms * 16 + m) * 128 + kk * 32 + quad * 8);
#pragma unroll
      for (int ns = 0; ns < 4; ++ns) {
        bf16x8 wf = *(const bf16x8*)(wS + ((size_t)(kk * 4 + quad) * 256 + nbp + ns * 16 + m) * 8);
#pragma unroll
        for (int ms = 0; ms < 4; ++ms)
          acc2[ms][ns] = __builtin_amdgcn_mfma_f32_16x16x32_bf16(xf[ms], wf, acc2[ms][ns], 0, 0, 0);
      }
    }
#pragma unroll
    for (int ns = 0; ns < 4; ++ns) {
      int n = nbp + ns * 16 + m;
      float bsv = bsc[n];
#pragma unroll
      for (int ms = 0; ms < 4; ++ms) {
        ushort4 u;
        u.x = f2bf(acc2[ms][ns][0] + bsv);
        u.y = f2bf(acc2[ms][ns][1] + bsv);
        u.z = f2bf(acc2[ms][ns][2] + bsv);
        u.w = f2bf(acc2[ms][ns][3] + bsv);
        *(ushort4*)(sb + n * 68 + ms * 16 + quad * 4) = u;
      }
    }
  }
  __syncthreads();
  // ---- phase 3c: combine + ReLU + coalesced NCHW store ----
  {
    int px = t & 63, chg = t >> 6;    // 8 groups x 32 ch
#pragma unroll 8
    for (int i = 0; i < 32; ++i) {
      int ch = chg * 32 + i;
      float v = bf2f(yb[ch * 68 + px]) + bf2f(sb[ch * 68 + px]);
      out[(((size_t)(b * 256 + ch) * 64 + h) * 64) + px] = fmaxf(v, 0.f);
    }
  }
}

extern "C" void kernel_launch(void* const* d_in, const int* in_sizes, int n_in,
                              void* d_out, int out_size, void* d_ws, size_t ws_size,
                              hipStream_t stream) {
  const float* x     = (const float*)d_in[0];
  const float* w_off = (const float*)d_in[1];
  const float* b_off = (const float*)d_in[2];
  const float* w_def = (const float*)d_in[3];
  const float* b_def = (const float*)d_in[4];
  const float* gamma = (const float*)d_in[5];
  const float* beta  = (const float*)d_in[6];
  const float* w_sc  = (const float*)d_in[7];
  const float* b_sc  = (const float*)d_in[8];
  float* out = (float*)d_out;

  char* ws = (char*)d_ws;
  unsigned short* xpad  = (unsigned short*)(ws + OFF_XPAD);
  unsigned short* wB    = (unsigned short*)(ws + OFF_WB);
  unsigned short* wS    = (unsigned short*)(ws + OFF_WS2);
  unsigned short* wO    = (unsigned short*)(ws + OFF_WO);
  float* partials       = (float*)(ws + OFF_PART);
  float* stats          = (float*)(ws + OFF_STAT);
  unsigned int* cnt     = (unsigned int*)(ws + OFF_CNT);

  hipMemsetAsync(cnt, 0, SZ_CNT, stream);
  k_prep<<<2480, 256, 0, stream>>>(x, w_def, w_sc, w_off, xpad, wB, wS, wO);
  k_coop<<<512, 512, 0, stream>>>(xpad, wB, wS, wO, b_off, b_def, gamma, beta, b_sc,
                                  partials, stats, cnt, out);
}

// Round 8
// 234.950 us; speedup vs baseline: 1.0458x; 1.0458x over previous
//
#include <hip/hip_runtime.h>
#include <hip/hip_bf16.h>

typedef __attribute__((ext_vector_type(8))) short bf16x8;
typedef __attribute__((ext_vector_type(4))) float f32x4;

__device__ __forceinline__ float bf2f(unsigned short u) {
  return __uint_as_float(((unsigned int)u) << 16);
}
__device__ __forceinline__ unsigned short f2bf(float f) {
  unsigned int u = __float_as_uint(f);
  u += 0x7fffu + ((u >> 16) & 1u);
  return (unsigned short)(u >> 16);
}

// ---------------- workspace layout (bytes) ----------------
constexpr size_t OFF_XPAD = 0;
constexpr size_t SZ_XPAD  = (size_t)8 * 66 * 66 * 128 * 2;        // 8,921,088
constexpr size_t OFF_WB   = OFF_XPAD + SZ_XPAD;
constexpr size_t SZ_WB    = (size_t)9 * 16 * 256 * 8 * 2;         // 589,824
constexpr size_t OFF_WS2  = OFF_WB + SZ_WB;
constexpr size_t SZ_WS2   = (size_t)16 * 256 * 8 * 2;             // 65,536
constexpr size_t OFF_WO   = OFF_WS2 + SZ_WS2;
constexpr size_t SZ_WO    = (size_t)9 * 16 * 32 * 8 * 2;          // 73,728
constexpr size_t OFF_PART = OFF_WO + SZ_WO;
constexpr size_t SZ_PART  = (size_t)512 * 256 * 2 * 4;            // 1,048,576
constexpr size_t OFF_STAT = OFF_PART + SZ_PART;
constexpr size_t SZ_STAT  = (size_t)256 * 2 * 4;                  // 2,048
constexpr size_t OFF_CNT  = OFF_STAT + SZ_STAT;
constexpr size_t SZ_CNT   = 2 * 4;

// ---------------- device-scope grid barrier (proven in R7) ----------------
__device__ __forceinline__ void grid_barrier(unsigned int* cnt, unsigned int target) {
  __syncthreads();
  if (threadIdx.x == 0) {
    __threadfence();                  // release: make this block's writes device-visible
    __hip_atomic_fetch_add(cnt, 1u, __ATOMIC_ACQ_REL, __HIP_MEMORY_SCOPE_AGENT);
    while (__hip_atomic_load(cnt, __ATOMIC_ACQUIRE, __HIP_MEMORY_SCOPE_AGENT) < target) {
      __builtin_amdgcn_s_sleep(16);
    }
  }
  __syncthreads();
}

// ---------------- prep: pad-transpose x (incl. borders) + weight pack ----------------
__global__ __launch_bounds__(256) void k_prep(const float* __restrict__ x,
                                              const float* __restrict__ wdef,
                                              const float* __restrict__ wsc,
                                              const float* __restrict__ woff,
                                              unsigned short* __restrict__ xp,
                                              unsigned short* __restrict__ wB,
                                              unsigned short* __restrict__ wS,
                                              unsigned short* __restrict__ wO) {
  int blk = blockIdx.x;
  int t = threadIdx.x;
  if (blk < 1024) {                   // interior rows: NCHW fp32 -> NHWC bf16
    int b = blk >> 7, h = (blk >> 1) & 63, chalf = blk & 1;
    __shared__ float tile[16][66];
    for (int cc = 0; cc < 4; ++cc) {
      int c0 = (chalf * 4 + cc) * 16;
      int wr = t & 63, cl = t >> 6;
#pragma unroll
      for (int i = 0; i < 4; ++i) {
        int c = c0 + cl * 4 + i;
        tile[cl * 4 + i][wr] = x[(((size_t)b * 128 + c) * 64 + h) * 64 + wr];
      }
      __syncthreads();
      int ww = t >> 2, cq = t & 3;
      ushort4 u4;
      u4.x = f2bf(tile[cq * 4 + 0][ww]);
      u4.y = f2bf(tile[cq * 4 + 1][ww]);
      u4.z = f2bf(tile[cq * 4 + 2][ww]);
      u4.w = f2bf(tile[cq * 4 + 3][ww]);
      *(ushort4*)(xp + ((size_t)(b * 66 + h + 1) * 66 + (ww + 1)) * 128 + c0 + cq * 4) = u4;
      __syncthreads();
    }
  } else if (blk < 1040) {            // border rows (hp = 0 or 65): zeros
    int idx = blk - 1024;
    int b = idx >> 1, hp = (idx & 1) ? 65 : 0;
    unsigned short* base = xp + (size_t)(b * 66 + hp) * 66 * 128;
    uint4 z = {0u, 0u, 0u, 0u};
#pragma unroll
    for (int it = 0; it < 5; ++it) {
      int i = it * 256 + t;
      if (i < 1056) *(uint4*)(base + i * 8) = z;
    }
  } else if (blk < 1056) {            // border cols (px = 0 or 65), rows 1..64: zeros
    int idx = blk - 1040;
    int b = idx >> 1, px = (idx & 1) ? 65 : 0;
    uint4 z = {0u, 0u, 0u, 0u};
#pragma unroll
    for (int it = 0; it < 4; ++it) {
      int row = it * 16 + (t >> 4);
      int off = t & 15;
      *(uint4*)(xp + ((size_t)(b * 66 + 1 + row) * 66 + px) * 128 + off * 8) = z;
    }
  } else {                            // weight packing
    int tid = (blk - 1056) * 256 + t;
    if (tid < 294912) {
      int k8 = tid & 7, n = (tid >> 3) & 255, kb = (tid >> 11) & 15, tap = tid >> 15;
      int c = kb * 8 + k8;
      wB[tid] = f2bf(wdef[((size_t)n * 128 + c) * 9 + tap]);
    } else if (tid < 294912 + 32768) {
      int i = tid - 294912;
      int k8 = i & 7, n = (i >> 3) & 255, kb = i >> 11;
      wS[i] = f2bf(wsc[(size_t)n * 128 + kb * 8 + k8]);
    } else if (tid < 294912 + 32768 + 36864) {
      int i = tid - 327680;
      int k8 = i & 7, n = (i >> 3) & 31, kb = (i >> 8) & 15, tap = i >> 12;
      int c = kb * 8 + k8;
      wO[i] = f2bf(n < 18 ? woff[((size_t)n * 128 + c) * 9 + tap] : 0.f);
    }
  }
}

// ---------------- fused: R3 k_main body + grid-barrier BN + in-register finale ----------------
// 512 blocks x 256 thr (4 waves), 64-px row tile, full 256 out-ch per block.
// launch_bounds(256,2): VGPR cap 256 (no starvation), guarantees 2 blocks/CU residency.
__global__ __launch_bounds__(256, 2) void k_fused(const unsigned short* __restrict__ xp,
                                                  const unsigned short* __restrict__ wB,
                                                  const unsigned short* __restrict__ wS,
                                                  const unsigned short* __restrict__ wO,
                                                  const float* __restrict__ boff,
                                                  const float* __restrict__ bdef,
                                                  const float* __restrict__ gamma,
                                                  const float* __restrict__ beta,
                                                  const float* __restrict__ bsc,
                                                  float* __restrict__ partials,
                                                  float* __restrict__ stats,
                                                  unsigned int* __restrict__ cnt,
                                                  float* __restrict__ out) {
  int rt = blockIdx.x;                // rowtile: b*64 + h
  int b = rt >> 6, h = rt & 63;
  int t = threadIdx.x;
  int lane = t & 63, wid = t >> 6;    // 4 waves
  int m = lane & 15, quad = lane >> 4;
  __shared__ __align__(16) unsigned short At[2][64 * 136];  // 34816 B (reused as yb)
  __shared__ float offsL[9][64][2];                          // 4608 B

  // ---- phase 0: inline offset conv (R3 verbatim) ----
  {
    f32x4 a0 = {0.f, 0.f, 0.f, 0.f}, a1 = {0.f, 0.f, 0.f, 0.f};
    int px = wid * 16 + m;
    const unsigned short* xbase = xp + ((size_t)(b * 66 + h) * 66 + px) * 128 + quad * 8;
    for (int tap = 0; tap < 9; ++tap) {
      const unsigned short* arow = xbase + ((tap / 3) * 66 + (tap % 3)) * 128;
#pragma unroll
      for (int kk = 0; kk < 4; ++kk) {
        bf16x8 a = *(const bf16x8*)(arow + kk * 32);
        const unsigned short* bb = wO + (size_t)(tap * 16 + kk * 4 + quad) * 256;
        bf16x8 b0 = *(const bf16x8*)(bb + m * 8);
        bf16x8 b1 = *(const bf16x8*)(bb + (16 + m) * 8);
        a0 = __builtin_amdgcn_mfma_f32_16x16x32_bf16(a, b0, a0, 0, 0, 0);
        a1 = __builtin_amdgcn_mfma_f32_16x16x32_bf16(a, b1, a1, 0, 0, 0);
      }
    }
#pragma unroll
    for (int r = 0; r < 4; ++r) {
      int pxs = wid * 16 + quad * 4 + r;
      offsL[m >> 1][pxs][m & 1] = a0[r] + boff[m];
      if (m < 2) offsL[8][pxs][m] = a1[r] + boff[16 + m];
    }
  }
  __syncthreads();

  f32x4 acc[4][4];
#pragma unroll
  for (int i = 0; i < 4; ++i)
#pragma unroll
    for (int j = 0; j < 4; ++j) acc[i][j] = (f32x4){0.f, 0.f, 0.f, 0.f};

  int px_s = t >> 2, sub = t & 3;     // sampling role (R3 verbatim)
  const unsigned short* xb_base = xp + (size_t)b * 66 * 66 * 128;
  int nb = wid * 64;

  auto sample_prep = [&](int tap, float* wgt, const unsigned short** p) {
    float2 ov = *(const float2*)&offsL[tap][px_s][0];
    int ky = tap / 3 - 1, kx = tap % 3 - 1;
    float py = (float)(h + ky) + ov.x;
    float pxf = (float)(px_s + kx) + ov.y;
    float y0f = floorf(py), x0f = floorf(pxf);
    float fy = py - y0f, fx = pxf - x0f;
    int iy0 = (int)y0f, ix0 = (int)x0f;
#pragma unroll
    for (int j = 0; j < 4; ++j) {
      int iy = iy0 + (j >> 1), ix = ix0 + (j & 1);
      float wy = (j >> 1) ? fy : 1.f - fy;
      float wx = (j & 1) ? fx : 1.f - fx;
      bool valid = (iy >= 0) && (iy < 64) && (ix >= 0) && (ix < 64);
      int iyc = min(max(iy, 0), 63), ixc = min(max(ix, 0), 63);
      wgt[j] = valid ? wy * wx : 0.f;
      p[j] = xb_base + ((size_t)(iyc + 1) * 66 + (ixc + 1)) * 128 + sub * 8;
    }
  };
  auto load_g2 = [&](const unsigned short** p, int g0, bf16x8 (*v)[4]) {
#pragma unroll
    for (int gg = 0; gg < 2; ++gg)
#pragma unroll
      for (int j = 0; j < 4; ++j)
        v[gg][j] = *(const bf16x8*)(p[j] + (g0 + gg) * 32);
  };
  auto store_g2 = [&](unsigned short* dst, int g0, const float* wgt, bf16x8 (*v)[4]) {
#pragma unroll
    for (int gg = 0; gg < 2; ++gg) {
      bf16x8 o;
#pragma unroll
      for (int j = 0; j < 8; ++j) {
        float s = fmaf(wgt[0], bf2f((unsigned short)v[gg][0][j]),
                  fmaf(wgt[1], bf2f((unsigned short)v[gg][1][j]),
                  fmaf(wgt[2], bf2f((unsigned short)v[gg][2][j]),
                       wgt[3] * bf2f((unsigned short)v[gg][3][j]))));
        o[j] = (short)f2bf(s);
      }
      *(bf16x8*)(dst + (g0 + gg) * 32) = o;
    }
  };
  auto mfma_half = [&](const unsigned short* buf, int tap, int kk0) {
#pragma unroll
    for (int kk = kk0; kk < kk0 + 2; ++kk) {
      bf16x8 af[4];
#pragma unroll
      for (int ms = 0; ms < 4; ++ms)
        af[ms] = *(const bf16x8*)(buf + (ms * 16 + m) * 136 + kk * 32 + quad * 8);
#pragma unroll
      for (int ns = 0; ns < 4; ++ns) {
        bf16x8 bfr = *(const bf16x8*)(wB + ((size_t)(tap * 16 + kk * 4 + quad) * 256 + nb + ns * 16 + m) * 8);
#pragma unroll
        for (int ms = 0; ms < 4; ++ms)
          acc[ms][ns] = __builtin_amdgcn_mfma_f32_16x16x32_bf16(af[ms], bfr, acc[ms][ns], 0, 0, 0);
      }
    }
  };

  {
    float wgt[4]; const unsigned short* p[4]; bf16x8 v[2][4];
    sample_prep(0, wgt, p);
    unsigned short* dst = &At[0][px_s * 136 + sub * 8];
    load_g2(p, 0, v); store_g2(dst, 0, wgt, v);
    load_g2(p, 2, v); store_g2(dst, 2, wgt, v);
  }
#pragma unroll
  for (int tap = 0; tap < 9; ++tap) {
    __syncthreads();
    const unsigned short* cur = At[tap & 1];
    unsigned short* dst = &At[(tap + 1) & 1][px_s * 136 + sub * 8];
    if (tap < 8) {
      float wgt[4]; const unsigned short* p[4]; bf16x8 v[2][4];
      sample_prep(tap + 1, wgt, p);
      load_g2(p, 0, v);
      mfma_half(cur, tap, 0);
      store_g2(dst, 0, wgt, v);
      load_g2(p, 2, v);
      mfma_half(cur, tap, 2);
      store_g2(dst, 2, wgt, v);
    } else {
      mfma_half(cur, tap, 0);
      mfma_half(cur, tap, 2);
    }
  }

  // ---- BN partials straight from registers ----
#pragma unroll
  for (int ns = 0; ns < 4; ++ns) {
    int n = nb + ns * 16 + m;
    float bias = bdef[n];
    float s = 0.f, q = 0.f;
#pragma unroll
    for (int ms = 0; ms < 4; ++ms)
#pragma unroll
      for (int r = 0; r < 4; ++r) {
        float v = acc[ms][ns][r] + bias;
        s += v; q += v * v;
      }
    s += __shfl_xor(s, 16); s += __shfl_xor(s, 32);
    q += __shfl_xor(q, 16); q += __shfl_xor(q, 32);
    if (quad == 0) {
      partials[((size_t)rt * 256 + n) * 2 + 0] = s;
      partials[((size_t)rt * 256 + n) * 2 + 1] = q;
    }
  }

  grid_barrier(cnt + 0, 512);

  // ---- stats: blocks 0..255 each finalize one channel ----
  if (rt < 256) {
    int ch = rt;
    float s = partials[((size_t)t * 256 + ch) * 2 + 0]
            + partials[((size_t)(256 + t) * 256 + ch) * 2 + 0];
    float q = partials[((size_t)t * 256 + ch) * 2 + 1]
            + partials[((size_t)(256 + t) * 256 + ch) * 2 + 1];
#pragma unroll
    for (int d = 1; d < 64; d <<= 1) { s += __shfl_xor(s, d); q += __shfl_xor(q, d); }
    float* red = &offsL[0][0][0];
    if (lane == 0) { red[wid * 2] = s; red[wid * 2 + 1] = q; }
    __syncthreads();
    if (wid == 0 && lane < 4) {
      s = red[lane * 2]; q = red[lane * 2 + 1];
      s += __shfl_xor(s, 1); q += __shfl_xor(q, 1);
      s += __shfl_xor(s, 2); q += __shfl_xor(q, 2);
      if (lane == 0) {
        float mean = s * (1.f / 32768.f);
        float var = q * (1.f / 32768.f) - mean * mean;
        float A = gamma[ch] * rsqrtf(var + 1e-5f);
        stats[ch * 2 + 0] = A;
        stats[ch * 2 + 1] = beta[ch] - mean * A;
      }
    }
  }

  grid_barrier(cnt + 1, 512);

  // ---- finale: BN-apply in-register -> wave-local LDS transpose; shortcut MFMA; store ----
  unsigned short* yb = &At[0][0];     // [256 ch][68 px] bf16 = 34816 B
#pragma unroll
  for (int ns = 0; ns < 4; ++ns) {
    int n = nb + ns * 16 + m;
    float bias = bdef[n];
    float A = stats[n * 2], Bc = stats[n * 2 + 1];
#pragma unroll
    for (int ms = 0; ms < 4; ++ms) {
      ushort4 u;
      u.x = f2bf(fmaf(acc[ms][ns][0] + bias, A, Bc));
      u.y = f2bf(fmaf(acc[ms][ns][1] + bias, A, Bc));
      u.z = f2bf(fmaf(acc[ms][ns][2] + bias, A, Bc));
      u.w = f2bf(fmaf(acc[ms][ns][3] + bias, A, Bc));
      *(ushort4*)(yb + n * 68 + ms * 16 + quad * 4) = u;
    }
  }
  // shortcut: A = wS (D rows = ch), B = x row (D cols = px); wave covers its own nb ch range
  {
    const unsigned short* xrow = xp + ((size_t)(b * 66 + h + 1) * 66 + 1) * 128;
    f32x4 acc2[4][4];
#pragma unroll
    for (int i = 0; i < 4; ++i)
#pragma unroll
      for (int j = 0; j < 4; ++j) acc2[i][j] = (f32x4){0.f, 0.f, 0.f, 0.f};
#pragma unroll
    for (int kk = 0; kk < 4; ++kk) {
      bf16x8 xf[4];
#pragma unroll
      for (int pt = 0; pt < 4; ++pt)
        xf[pt] = *(const bf16x8*)(xrow + (pt * 16 + m) * 128 + kk * 32 + quad * 8);
#pragma unroll
      for (int ct = 0; ct < 4; ++ct) {
        bf16x8 wf = *(const bf16x8*)(wS + ((size_t)(kk * 4 + quad) * 256 + nb + ct * 16 + m) * 8);
#pragma unroll
        for (int pt = 0; pt < 4; ++pt)
          acc2[ct][pt] = __builtin_amdgcn_mfma_f32_16x16x32_bf16(wf, xf[pt], acc2[ct][pt], 0, 0, 0);
      }
    }
    // combine (wave-local rows of yb) + ReLU + coalesced NCHW store
#pragma unroll
    for (int ct = 0; ct < 4; ++ct) {
#pragma unroll
      for (int r = 0; r < 4; ++r) {
        int ch = nb + ct * 16 + quad * 4 + r;
        float bsv = bsc[ch];
#pragma unroll
        for (int pt = 0; pt < 4; ++pt) {
          int px = pt * 16 + m;
          float v = bf2f(yb[ch * 68 + px]) + acc2[ct][pt][r] + bsv;
          out[(((size_t)(b * 256 + ch) * 64 + h) * 64) + px] = fmaxf(v, 0.f);
        }
      }
    }
  }
}

extern "C" void kernel_launch(void* const* d_in, const int* in_sizes, int n_in,
                              void* d_out, int out_size, void* d_ws, size_t ws_size,
                              hipStream_t stream) {
  const float* x     = (const float*)d_in[0];
  const float* w_off = (const float*)d_in[1];
  const float* b_off = (const float*)d_in[2];
  const float* w_def = (const float*)d_in[3];
  const float* b_def = (const float*)d_in[4];
  const float* gamma = (const float*)d_in[5];
  const float* beta  = (const float*)d_in[6];
  const float* w_sc  = (const float*)d_in[7];
  const float* b_sc  = (const float*)d_in[8];
  float* out = (float*)d_out;

  char* ws = (char*)d_ws;
  unsigned short* xpad  = (unsigned short*)(ws + OFF_XPAD);
  unsigned short* wB    = (unsigned short*)(ws + OFF_WB);
  unsigned short* wS    = (unsigned short*)(ws + OFF_WS2);
  unsigned short* wO    = (unsigned short*)(ws + OFF_WO);
  float* partials       = (float*)(ws + OFF_PART);
  float* stats          = (float*)(ws + OFF_STAT);
  unsigned int* cnt     = (unsigned int*)(ws + OFF_CNT);

  hipMemsetAsync(cnt, 0, SZ_CNT, stream);
  k_prep<<<2480, 256, 0, stream>>>(x, w_def, w_sc, w_off, xpad, wB, wS, wO);
  k_fused<<<512, 256, 0, stream>>>(xpad, wB, wS, wO, b_off, b_def, gamma, beta, b_sc,
                                   partials, stats, cnt, out);
}